// Round 15
// baseline (1846.588 us; speedup 1.0000x reference)
//
#include <hip/hip_runtime.h>

#define B_ 4
#define C_ 512
#define N_ 4096   // H*W == M (style spatial) == N (content spatial)

typedef unsigned short u16;
typedef _Float16 f16;
typedef f16 f16x8 __attribute__((ext_vector_type(8)));
typedef float f32x4 __attribute__((ext_vector_type(4)));

#define MFMA16(a, b, c) __builtin_amdgcn_mfma_f32_16x16x32_f16(a, b, c, 0, 0, 0)

// async global->LDS, 16B/lane; dest = wave-uniform base + lane*16 (HW rule)
#define GLD16(gsrc, ldst)                                                                  \
  __builtin_amdgcn_global_load_lds((const __attribute__((address_space(1))) void*)(gsrc),  \
                                   (__attribute__((address_space(3))) void*)(ldst), 16, 0, 0)

__device__ __forceinline__ u16 f2h(float f) {
  union { f16 h; u16 u; } x; x.h = (f16)f; return x.u;   // v_cvt_f16_f32, RNE
}
__device__ __forceinline__ float h2f(u16 v) {
  union { u16 u; f16 h; } x; x.u = v; return (float)x.h;
}
__device__ __forceinline__ f16x8 ldA(const void* p) {
  union { uint4 u; f16x8 v; } x; x.u = *(const uint4*)p; return x.v;
}

// ---------------- weights fp32 -> f16 ----------------
__global__ __launch_bounds__(256) void cast_w_kernel(const float* __restrict__ in,
                                                     u16* __restrict__ out, int n) {
  int i = (blockIdx.x * 256 + threadIdx.x) * 4;
  if (i >= n) return;
  float4 v = *(const float4*)(in + i);
  uint2 p;
  p.x = f2h(v.x) | ((unsigned)f2h(v.y) << 16);
  p.y = f2h(v.z) | ((unsigned)f2h(v.w) << 16);
  *(uint2*)(out + i) = p;
}

// ---------------- fp32 [B][C][N] -> f16 [B][N][C] ----------------
__global__ __launch_bounds__(256) void transpose_cast_kernel(const float* __restrict__ in,
                                                             u16* __restrict__ out) {
  __shared__ float ld[64][65];
  const int b = blockIdx.z, n0 = blockIdx.x * 64, c0 = blockIdx.y * 64;
  const int t = threadIdx.x;
  {
    const int r = t >> 2, q4 = (t & 3) * 16;
    const float* ip = in + ((size_t)(b * C_ + c0 + r)) * N_ + n0 + q4;
#pragma unroll
    for (int j = 0; j < 4; ++j) {
      float4 v = *(const float4*)(ip + j * 4);
      ld[r][q4 + j * 4 + 0] = v.x; ld[r][q4 + j * 4 + 1] = v.y;
      ld[r][q4 + j * 4 + 2] = v.z; ld[r][q4 + j * 4 + 3] = v.w;
    }
  }
  __syncthreads();
  {
    const int r2 = t >> 2, c16 = (t & 3) * 16;
    unsigned pk[8];
#pragma unroll
    for (int j = 0; j < 8; ++j) {
      unsigned lo = f2h(ld[c16 + j * 2 + 0][r2]);
      unsigned hi = f2h(ld[c16 + j * 2 + 1][r2]);
      pk[j] = lo | (hi << 16);
    }
    u16* op = out + ((size_t)(b * N_ + n0 + r2)) * C_ + c0 + c16;
    *(uint4*)(op + 0) = make_uint4(pk[0], pk[1], pk[2], pk[3]);
    *(uint4*)(op + 8) = make_uint4(pk[4], pk[5], pk[6], pk[7]);
  }
}

// ------------- f16 [B][M][C] -> f16 [B][C][M] -------------
__global__ __launch_bounds__(256) void transpose_h_kernel(const u16* __restrict__ in,
                                                          u16* __restrict__ outV) {
  __shared__ u16 ldt[64][72];
  const int b = blockIdx.z, m0 = blockIdx.x * 64, c0 = blockIdx.y * 64;
  const int t = threadIdx.x;
  {
    const int r = t >> 2, q4 = (t & 3) * 16;
    const u16* ip = in + ((size_t)(b * N_ + m0 + r)) * C_ + c0 + q4;
    *(uint4*)&ldt[r][q4 + 0] = *(const uint4*)(ip + 0);
    *(uint4*)&ldt[r][q4 + 8] = *(const uint4*)(ip + 8);
  }
  __syncthreads();
  {
    const int rc = t >> 2, m16 = (t & 3) * 16;
    unsigned pv[8];
#pragma unroll
    for (int j = 0; j < 8; ++j) {
      unsigned v0 = ldt[m16 + j * 2 + 0][rc];
      unsigned v1 = ldt[m16 + j * 2 + 1][rc];
      pv[j] = v0 | (v1 << 16);
    }
    size_t ob = ((size_t)(b * C_ + c0 + rc)) * N_ + m0 + m16;
    *(uint4*)(outV + ob + 0) = make_uint4(pv[0], pv[1], pv[2], pv[3]);
    *(uint4*)(outV + ob + 8) = make_uint4(pv[4], pv[5], pv[6], pv[7]);
  }
}

// ---------------- conv1x1: out[b][n][o] = sum_c Xt[b][n][c]*W[o][c] + bias[o] ----------------
__global__ __launch_bounds__(512, 4) void conv_kernel(const u16* __restrict__ Xt,
                                                      const u16* __restrict__ Wb,
                                                      const float* __restrict__ bias,
                                                      u16* __restrict__ Outp) {
  __shared__ char sm[65536];
  const int b = blockIdx.z, n0 = blockIdx.x * 64, o0 = blockIdx.y * 64;
  const int t = threadIdx.x, w = t >> 6, lane = t & 63;
  const int wr = w >> 1, wc = w & 1, l15 = lane & 15, l4 = lane >> 4;
#pragma unroll
  for (int k = 0; k < 8; ++k) {
    int ch = t + k * 512, row = ch >> 6, c16 = ch & 63;
    uint4 xv = *(const uint4*)(Xt + ((size_t)(b * N_ + n0 + row)) * C_ + c16 * 8);
    *(uint4*)(sm + row * 1024 + ((c16 ^ (row & 7)) << 4)) = xv;
  }
  __syncthreads();
  f32x4 acc0 = {0, 0, 0, 0}, acc1 = {0, 0, 0, 0};
  const int arow = wr * 16 + l15;
  const int oA = o0 + wc * 32 + l15, oB = oA + 16;
  const u16* wp0 = Wb + (size_t)oA * C_ + l4 * 8;
  const u16* wp1 = Wb + (size_t)oB * C_ + l4 * 8;
#pragma unroll
  for (int kf = 0; kf < 16; ++kf) {
    f16x8 a = ldA(sm + arow * 1024 + (((kf * 4 + l4) ^ (arow & 7)) << 4));
    f16x8 w0 = ldA(wp0 + kf * 32);
    f16x8 w1 = ldA(wp1 + kf * 32);
    acc0 = MFMA16(a, w0, acc0);
    acc1 = MFMA16(a, w1, acc1);
  }
  const float b0 = bias[oA], b1 = bias[oB];
#pragma unroll
  for (int r = 0; r < 4; ++r) {
    int n = n0 + wr * 16 + l4 * 4 + r;
    size_t base = ((size_t)(b * N_ + n)) * C_;
    Outp[base + oA] = f2h(acc0[r] + b0);
    Outp[base + oB] = f2h(acc1[r] + b1);
  }
}

// ====== fused dual-moment flash attention — async GLD staging, pre-swizzled sources ======
// OutM[b][n][c] (f32) = softmax(F G) @ V^T ; OutS = softmax(F G) @ (V^2)^T
// R14 structure; staging via global_load_lds (G21: LINEAR LDS dest = 16*ch, XOR swizzle
// applied to the GLOBAL source column; read-side code unchanged since swizzle is an
// involution). Zero staging registers. V(it) issued at B2 (hidden under softmax +
// rescale); G(it+1) issued after B4.
#define LQ  0        // Q tile [64 n][512 c] f16, xor-swizzled rows of 1024B
#define LGV 65536    // G [64 m][512 c] (QK) / V [512 c][64 m] (PV), time-shared
#define LS  131072   // S tile [64 n][64 m] f16, xor-swizzled rows of 128B
#define LPM 139264   // pmax float [4][64]
#define LPS 140288   // psum float [4][64]

__global__ __launch_bounds__(1024, 4) void attn_dual_kernel(const u16* __restrict__ Ft,
                                                            const u16* __restrict__ Gt,
                                                            const u16* __restrict__ V,
                                                            float* __restrict__ OutM,
                                                            float* __restrict__ OutS) {
  __shared__ char sm[141312];
  char* ldsQ = sm + LQ; char* ldsGV = sm + LGV; char* ldsS = sm + LS;
  float* pmax = (float*)(sm + LPM);
  float* psum = (float*)(sm + LPS);

  const int b = blockIdx.y, n0 = blockIdx.x * 64;
  const int t = threadIdx.x, w = t >> 6, lane = t & 63;
  const int ri = w >> 2, mi = w & 3;                    // QK: row-group x m-quarter; PV: row-group x c-eighth
  const int l15 = lane & 15, l4 = lane >> 4;
  const int wbase = (t & 960) << 4;                     // w*64*16: wave-uniform LDS chunk base

  // ---- prologue: stage Q once (register path, one-time); issue GLD G(0) ----
#pragma unroll
  for (int k = 0; k < 4; ++k) {
    int ch = t + k * 1024, row = ch >> 6, c16 = ch & 63;
    uint4 qv = *(const uint4*)(Ft + ((size_t)(b * N_ + n0 + row)) * C_ + c16 * 8);
    *(uint4*)(ldsQ + row * 1024 + ((c16 ^ (row & 7)) << 4)) = qv;
  }
#pragma unroll
  for (int k = 0; k < 4; ++k) {                         // G(0): src col pre-swizzled
    int ch = t + k * 1024, row = ch >> 6, c16 = ch & 63;
    const u16* src = Gt + ((size_t)(b * N_ + row)) * C_ + (((c16 ^ (row & 7)) & 63) << 3);
    GLD16(src, ldsGV + wbase + (k << 14));
  }

  f32x4 accM[8], accS[8];
#pragma unroll
  for (int i = 0; i < 8; ++i) { accM[i] = (f32x4){0,0,0,0}; accS[i] = (f32x4){0,0,0,0}; }
  float m_run[4] = {-1e30f, -1e30f, -1e30f, -1e30f};
  float l_run[4] = {0, 0, 0, 0};

  const u16* Vb = V + (size_t)(b * C_) * N_;
  __syncthreads();                                      // B1: Q + G(0) resident (vmcnt drained)

  for (int it = 0; it < 64; ++it) {
    const int m0 = it * 64;
    // ---- QK^T: wave -> S[16 n (ri) x 16 m (mi)] ----
    f32x4 s0 = {0, 0, 0, 0};
    {
      const int qrow = ri * 16 + l15;
      const int grow = mi * 16 + l15;
#pragma unroll
      for (int kf = 0; kf < 16; ++kf) {
        f16x8 qf = ldA(ldsQ + qrow * 1024 + (((kf * 4 + l4) ^ (qrow & 7)) << 4));
        f16x8 gf = ldA(ldsGV + grow * 1024 + (((kf * 4 + l4) ^ (grow & 7)) << 4));
        s0 = MFMA16(qf, gf, s0);
      }
    }
    // quarter row-max (16-lane butterfly) -> pmax
    float rmax[4];
#pragma unroll
    for (int r = 0; r < 4; ++r) rmax[r] = s0[r];
#pragma unroll
    for (int off = 1; off < 16; off <<= 1)
#pragma unroll
      for (int r = 0; r < 4; ++r) rmax[r] = fmaxf(rmax[r], __shfl_xor(rmax[r], off));
    if (l15 == 0)
#pragma unroll
      for (int r = 0; r < 4; ++r) pmax[mi * 64 + ri * 16 + l4 * 4 + r] = rmax[r];
    __syncthreads();                                    // B2: pmax ready; ALL G reads done

    // ---- issue GLD V(it) into shared buffer (G dead); latency hides under softmax ----
#pragma unroll
    for (int k = 0; k < 4; ++k) {
      int ch = t + k * 1024, c = ch >> 3, sl = ch & 7;
      const u16* src = Vb + (size_t)c * N_ + m0 + ((sl ^ (c & 7)) << 3);
      GLD16(src, ldsGV + wbase + (k << 14));
    }
    // ---- softmax + rescale (register/VALU work covering V arrival) ----
    float fac[4], mnew[4], rsum[4];
#pragma unroll
    for (int r = 0; r < 4; ++r) {
      int row = ri * 16 + l4 * 4 + r;
      float mt = fmaxf(fmaxf(pmax[row], pmax[64 + row]),
                       fmaxf(pmax[128 + row], pmax[192 + row]));
      float mn = fmaxf(m_run[r], mt);
      fac[r] = __expf(m_run[r] - mn);
      m_run[r] = mn; mnew[r] = mn;
    }
#pragma unroll
    for (int r = 0; r < 4; ++r) {
      float p0 = __expf(s0[r] - mnew[r]);
      u16 pb0 = f2h(p0);
      rsum[r] = h2f(pb0);                               // denominator from ROUNDED p
      int row = ri * 16 + l4 * 4 + r;
      int m = mi * 16 + l15;
      *(u16*)(ldsS + row * 128 + (((m >> 3) ^ (row & 7)) << 4) + (m & 7) * 2) = pb0;
    }
#pragma unroll
    for (int off = 1; off < 16; off <<= 1)
#pragma unroll
      for (int r = 0; r < 4; ++r) rsum[r] += __shfl_xor(rsum[r], off);
    if (l15 == 0)
#pragma unroll
      for (int r = 0; r < 4; ++r) psum[mi * 64 + ri * 16 + l4 * 4 + r] = rsum[r];
    // acc rescale moved INTO this window (regs only) to extend V cover
    bool nch = true;
#pragma unroll
    for (int r = 0; r < 4; ++r) nch = nch && (fac[r] == 1.0f);
    if (!__all(nch)) {
#pragma unroll
      for (int f = 0; f < 8; ++f)
#pragma unroll
        for (int r = 0; r < 4; ++r) { accM[f][r] *= fac[r]; accS[f][r] *= fac[r]; }
    }
    __syncthreads();                                    // B3: V arrived + S + psum visible

    // ---- l update + dual PV (S and V from LDS) ----
#pragma unroll
    for (int r = 0; r < 4; ++r) {
      int row = ri * 16 + l4 * 4 + r;
      l_run[r] = l_run[r] * fac[r] +
                 ((psum[row] + psum[64 + row]) + (psum[128 + row] + psum[192 + row]));
    }
    const int srow = ri * 16 + l15;
    f16x8 a0 = ldA(ldsS + srow * 128 + (((0 + l4) ^ (srow & 7)) << 4));
    f16x8 a1 = ldA(ldsS + srow * 128 + (((4 + l4) ^ (srow & 7)) << 4));
#pragma unroll
    for (int f = 0; f < 8; ++f) {
      const int c = mi * 128 + f * 16 + l15;
      f16x8 v0 = ldA(ldsGV + c * 128 + (((0 + l4) ^ (c & 7)) << 4));
      f16x8 v1 = ldA(ldsGV + c * 128 + (((4 + l4) ^ (c & 7)) << 4));
      accM[f] = MFMA16(a0, v0, accM[f]);
      accM[f] = MFMA16(a1, v1, accM[f]);
      f16x8 w0 = v0 * v0, w1 = v1 * v1;                 // f16 RNE squares
      accS[f] = MFMA16(a0, w0, accS[f]);
      accS[f] = MFMA16(a1, w1, accS[f]);
    }
    __syncthreads();                                    // B4: PV V-reads done; buffer free

    // ---- issue GLD G(it+1) ----
    if (it < 63) {
#pragma unroll
      for (int k = 0; k < 4; ++k) {
        int ch = t + k * 1024, row = ch >> 6, c16 = ch & 63;
        const u16* src = Gt + ((size_t)(b * N_ + m0 + 64 + row)) * C_ +
                         (((c16 ^ (row & 7)) & 63) << 3);
        GLD16(src, ldsGV + wbase + (k << 14));
      }
    }
    __syncthreads();                                    // B1': G(it+1) resident
  }

  // ---- epilogue: f32 outputs ----
  float rl[4];
#pragma unroll
  for (int r = 0; r < 4; ++r) rl[r] = 1.0f / l_run[r];
#pragma unroll
  for (int f = 0; f < 8; ++f) {
    const int c = mi * 128 + f * 16 + l15;
#pragma unroll
    for (int r = 0; r < 4; ++r) {
      int n = n0 + ri * 16 + l4 * 4 + r;
      size_t o = ((size_t)(b * N_ + n)) * C_ + c;
      OutM[o] = accM[f][r] * rl[r];
      OutS[o] = accS[f][r] * rl[r];
    }
  }
}

// ---------------- per-(b,c) content stats ----------------
__global__ __launch_bounds__(256) void stats_kernel(const float* __restrict__ content,
                                                    float* __restrict__ stats) {
  const int c = blockIdx.x, b = blockIdx.y;
  const float4* p = (const float4*)(content + ((size_t)(b * C_ + c)) * N_);
  float s = 0.f, ss = 0.f;
  for (int i = threadIdx.x; i < N_ / 4; i += 256) {
    float4 v = p[i];
    s += v.x + v.y + v.z + v.w;
    ss += v.x * v.x + v.y * v.y + v.z * v.z + v.w * v.w;
  }
#pragma unroll
  for (int off = 32; off; off >>= 1) { s += __shfl_down(s, off); ss += __shfl_down(ss, off); }
  __shared__ float as_[4], ass_[4];
  int w = threadIdx.x >> 6;
  if ((threadIdx.x & 63) == 0) { as_[w] = s; ass_[w] = ss; }
  __syncthreads();
  if (threadIdx.x == 0) {
    float S = as_[0] + as_[1] + as_[2] + as_[3];
    float SS = ass_[0] + ass_[1] + ass_[2] + ass_[3];
    float mu = S * (1.0f / N_);
    float var = (SS - (float)N_ * mu * mu) * (1.0f / (N_ - 1));
    stats[(size_t)(b * C_ + c) * 2 + 0] = mu;
    stats[(size_t)(b * C_ + c) * 2 + 1] = rsqrtf(var + 1e-5f);
  }
}

// ---------------- out[b][c][n] = sqrt(relu(sec-mean^2))*(x-mu)*rs + mean ----------------
__global__ __launch_bounds__(256) void combine_kernel(const float* __restrict__ content,
                                                      const float* __restrict__ meanb,
                                                      const float* __restrict__ secb,
                                                      const float* __restrict__ stats,
                                                      float* __restrict__ outp) {
  __shared__ float ldM[64][65], ldS[64][65];
  const int b = blockIdx.z, n0 = blockIdx.x * 64, c0 = blockIdx.y * 64;
  const int t = threadIdx.x;
  {
    const int r = t >> 2, q4 = (t & 3) * 16;
    size_t ib = ((size_t)(b * N_ + n0 + r)) * C_ + c0 + q4;
#pragma unroll
    for (int j = 0; j < 4; ++j) {
      float4 mv = *(const float4*)(meanb + ib + j * 4);
      float4 sv = *(const float4*)(secb + ib + j * 4);
      ldM[r][q4 + j * 4 + 0] = mv.x; ldM[r][q4 + j * 4 + 1] = mv.y;
      ldM[r][q4 + j * 4 + 2] = mv.z; ldM[r][q4 + j * 4 + 3] = mv.w;
      ldS[r][q4 + j * 4 + 0] = sv.x; ldS[r][q4 + j * 4 + 1] = sv.y;
      ldS[r][q4 + j * 4 + 2] = sv.z; ldS[r][q4 + j * 4 + 3] = sv.w;
    }
  }
  __syncthreads();
  const int n4 = (t & 15) * 4, cb = t >> 4;
#pragma unroll
  for (int cc = 0; cc < 4; ++cc) {
    int c_loc = cc * 16 + cb;
    int c = c0 + c_loc;
    float mu = stats[(size_t)(b * C_ + c) * 2 + 0];
    float rs = stats[(size_t)(b * C_ + c) * 2 + 1];
    size_t gb = ((size_t)(b * C_ + c)) * N_ + n0 + n4;
    float4 xv = *(const float4*)(content + gb);
    float4 ov;
    {
      float m0_ = ldM[n4 + 0][c_loc], s0_ = ldS[n4 + 0][c_loc];
      float m1_ = ldM[n4 + 1][c_loc], s1_ = ldS[n4 + 1][c_loc];
      float m2_ = ldM[n4 + 2][c_loc], s2_ = ldS[n4 + 2][c_loc];
      float m3_ = ldM[n4 + 3][c_loc], s3_ = ldS[n4 + 3][c_loc];
      ov.x = sqrtf(fmaxf(s0_ - m0_ * m0_, 0.f)) * ((xv.x - mu) * rs) + m0_;
      ov.y = sqrtf(fmaxf(s1_ - m1_ * m1_, 0.f)) * ((xv.y - mu) * rs) + m1_;
      ov.z = sqrtf(fmaxf(s2_ - m2_ * m2_, 0.f)) * ((xv.z - mu) * rs) + m2_;
      ov.w = sqrtf(fmaxf(s3_ - m3_ * m3_, 0.f)) * ((xv.w - mu) * rs) + m3_;
    }
    *(float4*)(outp + gb) = ov;
  }
}

extern "C" void kernel_launch(void* const* d_in, const int* in_sizes, int n_in,
                              void* d_out, int out_size, void* d_ws, size_t ws_size,
                              hipStream_t stream) {
  (void)in_sizes; (void)n_in; (void)out_size; (void)ws_size;
  const float* content = (const float*)d_in[0];
  const float* style   = (const float*)d_in[1];
  const float* ckey    = (const float*)d_in[2];
  const float* skey    = (const float*)d_in[3];
  const float* Wf = (const float*)d_in[4]; const float* bf_ = (const float*)d_in[5];
  const float* Wg = (const float*)d_in[6]; const float* bg_ = (const float*)d_in[7];
  const float* Wh = (const float*)d_in[8]; const float* bh_ = (const float*)d_in[9];
  float* outp = (float*)d_out;
  char* ws = (char*)d_ws;

  const size_t MB = 1u << 20;
  u16*   Ft    = (u16*)(ws + 0 * MB);    // [B][N][C] f16
  u16*   Gt    = (u16*)(ws + 16 * MB);   // [B][M][C] f16
  u16*   Hv    = (u16*)(ws + 32 * MB);   // [B][C][M] f16
  float* stats = (float*)(ws + 48 * MB); // [B][C][2] fp32 (after Xt dead)
  u16*   Xt    = (u16*)(ws + 48 * MB);   // scratch, dead after convH
  float* meanb = (float*)(ws + 64 * MB); // [B][N][C] fp32
  float* secb  = (float*)(ws + 96 * MB); // [B][N][C] fp32
  u16*   Hvt   = (u16*)(ws + 64 * MB);   // scratch, dead before attn
  u16*   Wb3   = (u16*)(ws + 80 * MB);   // weights, dead before attn
  u16* Wbf = Wb3, *Wbg = Wb3 + 262144, *Wbh = Wb3 + 524288;

  const dim3 gT(64, 8, 4);

  cast_w_kernel<<<256, 256, 0, stream>>>(Wf, Wbf, 262144);
  cast_w_kernel<<<256, 256, 0, stream>>>(Wg, Wbg, 262144);
  cast_w_kernel<<<256, 256, 0, stream>>>(Wh, Wbh, 262144);

  transpose_cast_kernel<<<gT, 256, 0, stream>>>(ckey, Xt);
  conv_kernel<<<gT, 512, 0, stream>>>(Xt, Wbf, bf_, Ft);
  transpose_cast_kernel<<<gT, 256, 0, stream>>>(skey, Xt);
  conv_kernel<<<gT, 512, 0, stream>>>(Xt, Wbg, bg_, Gt);
  transpose_cast_kernel<<<gT, 256, 0, stream>>>(style, Xt);
  conv_kernel<<<gT, 512, 0, stream>>>(Xt, Wbh, bh_, Hvt);
  transpose_h_kernel<<<gT, 256, 0, stream>>>(Hvt, Hv);

  stats_kernel<<<dim3(C_, B_), 256, 0, stream>>>(content, stats);
  attn_dual_kernel<<<dim3(64, B_), 1024, 0, stream>>>(Ft, Gt, Hv, meanb, secb);
  combine_kernel<<<gT, 256, 0, stream>>>(content, meanb, secb, stats, outp);
}

// Round 16
// 1133.697 us; speedup vs baseline: 1.6288x; 1.6288x over previous
//
#include <hip/hip_runtime.h>

#define B_ 4
#define C_ 512
#define N_ 4096   // H*W == M (style spatial) == N (content spatial)

typedef unsigned short u16;
typedef _Float16 f16;
typedef f16 f16x8 __attribute__((ext_vector_type(8)));
typedef float f32x4 __attribute__((ext_vector_type(4)));

#define MFMA16(a, b, c) __builtin_amdgcn_mfma_f32_16x16x32_f16(a, b, c, 0, 0, 0)

__device__ __forceinline__ u16 f2h(float f) {
  union { f16 h; u16 u; } x; x.h = (f16)f; return x.u;   // v_cvt_f16_f32, RNE
}
__device__ __forceinline__ float h2f(u16 v) {
  union { u16 u; f16 h; } x; x.u = v; return (float)x.h;
}
__device__ __forceinline__ f16x8 ldA(const void* p) {
  union { uint4 u; f16x8 v; } x; x.u = *(const uint4*)p; return x.v;
}

// ---------------- weights fp32 -> f16 ----------------
__global__ __launch_bounds__(256) void cast_w_kernel(const float* __restrict__ in,
                                                     u16* __restrict__ out, int n) {
  int i = (blockIdx.x * 256 + threadIdx.x) * 4;
  if (i >= n) return;
  float4 v = *(const float4*)(in + i);
  uint2 p;
  p.x = f2h(v.x) | ((unsigned)f2h(v.y) << 16);
  p.y = f2h(v.z) | ((unsigned)f2h(v.w) << 16);
  *(uint2*)(out + i) = p;
}

// ---------------- fp32 [B][C][N] -> f16 [B][N][C] ----------------
__global__ __launch_bounds__(256) void transpose_cast_kernel(const float* __restrict__ in,
                                                             u16* __restrict__ out) {
  __shared__ float ld[64][65];
  const int b = blockIdx.z, n0 = blockIdx.x * 64, c0 = blockIdx.y * 64;
  const int t = threadIdx.x;
  {
    const int r = t >> 2, q4 = (t & 3) * 16;
    const float* ip = in + ((size_t)(b * C_ + c0 + r)) * N_ + n0 + q4;
#pragma unroll
    for (int j = 0; j < 4; ++j) {
      float4 v = *(const float4*)(ip + j * 4);
      ld[r][q4 + j * 4 + 0] = v.x; ld[r][q4 + j * 4 + 1] = v.y;
      ld[r][q4 + j * 4 + 2] = v.z; ld[r][q4 + j * 4 + 3] = v.w;
    }
  }
  __syncthreads();
  {
    const int r2 = t >> 2, c16 = (t & 3) * 16;
    unsigned pk[8];
#pragma unroll
    for (int j = 0; j < 8; ++j) {
      unsigned lo = f2h(ld[c16 + j * 2 + 0][r2]);
      unsigned hi = f2h(ld[c16 + j * 2 + 1][r2]);
      pk[j] = lo | (hi << 16);
    }
    u16* op = out + ((size_t)(b * N_ + n0 + r2)) * C_ + c0 + c16;
    *(uint4*)(op + 0) = make_uint4(pk[0], pk[1], pk[2], pk[3]);
    *(uint4*)(op + 8) = make_uint4(pk[4], pk[5], pk[6], pk[7]);
  }
}

// ------------- f16 [B][M][C] -> f16 [B][C][M] -------------
__global__ __launch_bounds__(256) void transpose_h_kernel(const u16* __restrict__ in,
                                                          u16* __restrict__ outV) {
  __shared__ u16 ldt[64][72];
  const int b = blockIdx.z, m0 = blockIdx.x * 64, c0 = blockIdx.y * 64;
  const int t = threadIdx.x;
  {
    const int r = t >> 2, q4 = (t & 3) * 16;
    const u16* ip = in + ((size_t)(b * N_ + m0 + r)) * C_ + c0 + q4;
    *(uint4*)&ldt[r][q4 + 0] = *(const uint4*)(ip + 0);
    *(uint4*)&ldt[r][q4 + 8] = *(const uint4*)(ip + 8);
  }
  __syncthreads();
  {
    const int rc = t >> 2, m16 = (t & 3) * 16;
    unsigned pv[8];
#pragma unroll
    for (int j = 0; j < 8; ++j) {
      unsigned v0 = ldt[m16 + j * 2 + 0][rc];
      unsigned v1 = ldt[m16 + j * 2 + 1][rc];
      pv[j] = v0 | (v1 << 16);
    }
    size_t ob = ((size_t)(b * C_ + c0 + rc)) * N_ + m0 + m16;
    *(uint4*)(outV + ob + 0) = make_uint4(pv[0], pv[1], pv[2], pv[3]);
    *(uint4*)(outV + ob + 8) = make_uint4(pv[4], pv[5], pv[6], pv[7]);
  }
}

// ---------------- conv1x1: out[b][n][o] = sum_c Xt[b][n][c]*W[o][c] + bias[o] ----------------
__global__ __launch_bounds__(512, 4) void conv_kernel(const u16* __restrict__ Xt,
                                                      const u16* __restrict__ Wb,
                                                      const float* __restrict__ bias,
                                                      u16* __restrict__ Outp) {
  __shared__ char sm[65536];
  const int b = blockIdx.z, n0 = blockIdx.x * 64, o0 = blockIdx.y * 64;
  const int t = threadIdx.x, w = t >> 6, lane = t & 63;
  const int wr = w >> 1, wc = w & 1, l15 = lane & 15, l4 = lane >> 4;
#pragma unroll
  for (int k = 0; k < 8; ++k) {
    int ch = t + k * 512, row = ch >> 6, c16 = ch & 63;
    uint4 xv = *(const uint4*)(Xt + ((size_t)(b * N_ + n0 + row)) * C_ + c16 * 8);
    *(uint4*)(sm + row * 1024 + ((c16 ^ (row & 7)) << 4)) = xv;
  }
  __syncthreads();
  f32x4 acc0 = {0, 0, 0, 0}, acc1 = {0, 0, 0, 0};
  const int arow = wr * 16 + l15;
  const int oA = o0 + wc * 32 + l15, oB = oA + 16;
  const u16* wp0 = Wb + (size_t)oA * C_ + l4 * 8;
  const u16* wp1 = Wb + (size_t)oB * C_ + l4 * 8;
#pragma unroll
  for (int kf = 0; kf < 16; ++kf) {
    f16x8 a = ldA(sm + arow * 1024 + (((kf * 4 + l4) ^ (arow & 7)) << 4));
    f16x8 w0 = ldA(wp0 + kf * 32);
    f16x8 w1 = ldA(wp1 + kf * 32);
    acc0 = MFMA16(a, w0, acc0);
    acc1 = MFMA16(a, w1, acc1);
  }
  const float b0 = bias[oA], b1 = bias[oB];
#pragma unroll
  for (int r = 0; r < 4; ++r) {
    int n = n0 + wr * 16 + l4 * 4 + r;
    size_t base = ((size_t)(b * N_ + n)) * C_;
    Outp[base + oA] = f2h(acc0[r] + b0);
    Outp[base + oB] = f2h(acc1[r] + b1);
  }
}

// ====== fused dual-moment flash attention — R14 + T14 V-prefetch (static regs) ======
// OutM[b][n][c] (f32) = softmax(F G) @ V^T ; OutS = softmax(F G) @ (V^2)^T
// R14 structure (Q in LDS, G/V time-share one buffer, 4 barriers). Single change:
// V(it)'s 4 dwordx4 loads issue BEFORE the QK MFMA phase (HBM/L2 latency hides under
// QK + softmax); ds_writes stay post-psum. vpre[] fully statically indexed (rule #20).
#define LQ  0        // Q tile [64 n][512 c] f16, xor-swizzled rows of 1024B
#define LGV 65536    // G [64 m][512 c] (QK) / V [512 c][64 m] (PV), time-shared
#define LS  131072   // S tile [64 n][64 m] f16, xor-swizzled rows of 128B
#define LPM 139264   // pmax float [4][64]
#define LPS 140288   // psum float [4][64]

__global__ __launch_bounds__(1024, 4) void attn_dual_kernel(const u16* __restrict__ Ft,
                                                            const u16* __restrict__ Gt,
                                                            const u16* __restrict__ V,
                                                            float* __restrict__ OutM,
                                                            float* __restrict__ OutS) {
  __shared__ char sm[141312];
  char* ldsQ = sm + LQ; char* ldsGV = sm + LGV; char* ldsS = sm + LS;
  float* pmax = (float*)(sm + LPM);
  float* psum = (float*)(sm + LPS);

  const int b = blockIdx.y, n0 = blockIdx.x * 64;
  const int t = threadIdx.x, w = t >> 6, lane = t & 63;
  const int ri = w >> 2, mi = w & 3;                    // QK: row-group x m-quarter; PV: row-group x c-eighth
  const int l15 = lane & 15, l4 = lane >> 4;

  // ---- prologue: stage Q once ----
#pragma unroll
  for (int k = 0; k < 4; ++k) {
    int ch = t + k * 1024, row = ch >> 6, c16 = ch & 63;
    uint4 qv = *(const uint4*)(Ft + ((size_t)(b * N_ + n0 + row)) * C_ + c16 * 8);
    *(uint4*)(ldsQ + row * 1024 + ((c16 ^ (row & 7)) << 4)) = qv;
  }

  f32x4 accM[8], accS[8];
#pragma unroll
  for (int i = 0; i < 8; ++i) { accM[i] = (f32x4){0,0,0,0}; accS[i] = (f32x4){0,0,0,0}; }
  float m_run[4] = {-1e30f, -1e30f, -1e30f, -1e30f};
  float l_run[4] = {0, 0, 0, 0};

  // per-thread V staging decomposition (static): ch = t + k*1024 -> c = ch>>3, sl = ch&7
  const int vc = t >> 3, vsl = t & 7;                   // k advances c by 128
  const u16* Vb = V + (size_t)(b * C_) * N_;
  __syncthreads();                                      // Q resident

  for (int it = 0; it < 64; ++it) {
    const int m0 = it * 64;
    // ---- stage G(it) [64 m][512 c] (tight load->write) ----
#pragma unroll
    for (int k = 0; k < 4; ++k) {
      int ch = t + k * 1024, row = ch >> 6, c16 = ch & 63;
      uint4 gv = *(const uint4*)(Gt + ((size_t)(b * N_ + m0 + row)) * C_ + c16 * 8);
      *(uint4*)(ldsGV + row * 1024 + ((c16 ^ (row & 7)) << 4)) = gv;
    }
    __syncthreads();                                    // B1: G resident

    // ---- T14: issue V(it) loads NOW (latency hides under QK + softmax) ----
    uint4 vp0, vp1, vp2, vp3;                           // named, statically addressed
    {
      const u16* s0p = Vb + (size_t)(vc +   0) * N_ + m0 + vsl * 8;
      const u16* s1p = Vb + (size_t)(vc + 128) * N_ + m0 + vsl * 8;
      const u16* s2p = Vb + (size_t)(vc + 256) * N_ + m0 + vsl * 8;
      const u16* s3p = Vb + (size_t)(vc + 384) * N_ + m0 + vsl * 8;
      vp0 = *(const uint4*)s0p;
      vp1 = *(const uint4*)s1p;
      vp2 = *(const uint4*)s2p;
      vp3 = *(const uint4*)s3p;
    }

    // ---- QK^T: wave -> S[16 n (ri) x 16 m (mi)] ----
    f32x4 s0 = {0, 0, 0, 0};
    {
      const int qrow = ri * 16 + l15;
      const int grow = mi * 16 + l15;
#pragma unroll
      for (int kf = 0; kf < 16; ++kf) {
        f16x8 qf = ldA(ldsQ + qrow * 1024 + (((kf * 4 + l4) ^ (qrow & 7)) << 4));
        f16x8 gf = ldA(ldsGV + grow * 1024 + (((kf * 4 + l4) ^ (grow & 7)) << 4));
        s0 = MFMA16(qf, gf, s0);
      }
    }
    // quarter row-max (16-lane butterfly) -> pmax
    float rmax[4];
#pragma unroll
    for (int r = 0; r < 4; ++r) rmax[r] = s0[r];
#pragma unroll
    for (int off = 1; off < 16; off <<= 1)
#pragma unroll
      for (int r = 0; r < 4; ++r) rmax[r] = fmaxf(rmax[r], __shfl_xor(rmax[r], off));
    if (l15 == 0)
#pragma unroll
      for (int r = 0; r < 4; ++r) pmax[mi * 64 + ri * 16 + l4 * 4 + r] = rmax[r];
    __syncthreads();                                    // B2: pmax ready; ALL G reads done

    // ---- softmax (exchanged) ----
    float fac[4], mnew[4], rsum[4];
#pragma unroll
    for (int r = 0; r < 4; ++r) {
      int row = ri * 16 + l4 * 4 + r;
      float mt = fmaxf(fmaxf(pmax[row], pmax[64 + row]),
                       fmaxf(pmax[128 + row], pmax[192 + row]));
      float mn = fmaxf(m_run[r], mt);
      fac[r] = __expf(m_run[r] - mn);
      m_run[r] = mn; mnew[r] = mn;
    }
#pragma unroll
    for (int r = 0; r < 4; ++r) {
      float p0 = __expf(s0[r] - mnew[r]);
      u16 pb0 = f2h(p0);
      rsum[r] = h2f(pb0);                               // denominator from ROUNDED p
      int row = ri * 16 + l4 * 4 + r;
      int m = mi * 16 + l15;
      *(u16*)(ldsS + row * 128 + (((m >> 3) ^ (row & 7)) << 4) + (m & 7) * 2) = pb0;
    }
#pragma unroll
    for (int off = 1; off < 16; off <<= 1)
#pragma unroll
      for (int r = 0; r < 4; ++r) rsum[r] += __shfl_xor(rsum[r], off);
    if (l15 == 0)
#pragma unroll
      for (int r = 0; r < 4; ++r) psum[mi * 64 + ri * 16 + l4 * 4 + r] = rsum[r];

    // ---- ds_write V(it) from the prefetched registers (G dead since B2) ----
    {
      const int swz = (vsl ^ (vc & 7)) << 4;            // same involution as reads
      *(uint4*)(ldsGV + (vc +   0) * 128 + ((vsl ^ ((vc +   0) & 7)) << 4)) = vp0;
      *(uint4*)(ldsGV + (vc + 128) * 128 + ((vsl ^ ((vc + 128) & 7)) << 4)) = vp1;
      *(uint4*)(ldsGV + (vc + 256) * 128 + ((vsl ^ ((vc + 256) & 7)) << 4)) = vp2;
      *(uint4*)(ldsGV + (vc + 384) * 128 + ((vsl ^ ((vc + 384) & 7)) << 4)) = vp3;
      (void)swz;
    }
    __syncthreads();                                    // B3: V + S + psum ready

    // ---- l update, rescale, dual PV (S and V from LDS) ----
#pragma unroll
    for (int r = 0; r < 4; ++r) {
      int row = ri * 16 + l4 * 4 + r;
      l_run[r] = l_run[r] * fac[r] +
                 ((psum[row] + psum[64 + row]) + (psum[128 + row] + psum[192 + row]));
    }
    bool nch = true;
#pragma unroll
    for (int r = 0; r < 4; ++r) nch = nch && (fac[r] == 1.0f);
    if (!__all(nch)) {
#pragma unroll
      for (int f = 0; f < 8; ++f)
#pragma unroll
        for (int r = 0; r < 4; ++r) { accM[f][r] *= fac[r]; accS[f][r] *= fac[r]; }
    }
    const int srow = ri * 16 + l15;
    f16x8 a0 = ldA(ldsS + srow * 128 + (((0 + l4) ^ (srow & 7)) << 4));
    f16x8 a1 = ldA(ldsS + srow * 128 + (((4 + l4) ^ (srow & 7)) << 4));
#pragma unroll
    for (int f = 0; f < 8; ++f) {
      const int c = mi * 128 + f * 16 + l15;
      f16x8 v0 = ldA(ldsGV + c * 128 + (((0 + l4) ^ (c & 7)) << 4));
      f16x8 v1 = ldA(ldsGV + c * 128 + (((4 + l4) ^ (c & 7)) << 4));
      accM[f] = MFMA16(a0, v0, accM[f]);
      accM[f] = MFMA16(a1, v1, accM[f]);
      f16x8 w0 = v0 * v0, w1 = v1 * v1;                 // f16 RNE squares
      accS[f] = MFMA16(a0, w0, accS[f]);
      accS[f] = MFMA16(a1, w1, accS[f]);
    }
    __syncthreads();                                    // B4: PV V-reads done; buffer free
  }

  // ---- epilogue: f32 outputs ----
  float rl[4];
#pragma unroll
  for (int r = 0; r < 4; ++r) rl[r] = 1.0f / l_run[r];
#pragma unroll
  for (int f = 0; f < 8; ++f) {
    const int c = mi * 128 + f * 16 + l15;
#pragma unroll
    for (int r = 0; r < 4; ++r) {
      int n = n0 + ri * 16 + l4 * 4 + r;
      size_t o = ((size_t)(b * N_ + n)) * C_ + c;
      OutM[o] = accM[f][r] * rl[r];
      OutS[o] = accS[f][r] * rl[r];
    }
  }
}

// ---------------- per-(b,c) content stats ----------------
__global__ __launch_bounds__(256) void stats_kernel(const float* __restrict__ content,
                                                    float* __restrict__ stats) {
  const int c = blockIdx.x, b = blockIdx.y;
  const float4* p = (const float4*)(content + ((size_t)(b * C_ + c)) * N_);
  float s = 0.f, ss = 0.f;
  for (int i = threadIdx.x; i < N_ / 4; i += 256) {
    float4 v = p[i];
    s += v.x + v.y + v.z + v.w;
    ss += v.x * v.x + v.y * v.y + v.z * v.z + v.w * v.w;
  }
#pragma unroll
  for (int off = 32; off; off >>= 1) { s += __shfl_down(s, off); ss += __shfl_down(ss, off); }
  __shared__ float as_[4], ass_[4];
  int w = threadIdx.x >> 6;
  if ((threadIdx.x & 63) == 0) { as_[w] = s; ass_[w] = ss; }
  __syncthreads();
  if (threadIdx.x == 0) {
    float S = as_[0] + as_[1] + as_[2] + as_[3];
    float SS = ass_[0] + ass_[1] + ass_[2] + ass_[3];
    float mu = S * (1.0f / N_);
    float var = (SS - (float)N_ * mu * mu) * (1.0f / (N_ - 1));
    stats[(size_t)(b * C_ + c) * 2 + 0] = mu;
    stats[(size_t)(b * C_ + c) * 2 + 1] = rsqrtf(var + 1e-5f);
  }
}

// ---------------- out[b][c][n] = sqrt(relu(sec-mean^2))*(x-mu)*rs + mean ----------------
__global__ __launch_bounds__(256) void combine_kernel(const float* __restrict__ content,
                                                      const float* __restrict__ meanb,
                                                      const float* __restrict__ secb,
                                                      const float* __restrict__ stats,
                                                      float* __restrict__ outp) {
  __shared__ float ldM[64][65], ldS[64][65];
  const int b = blockIdx.z, n0 = blockIdx.x * 64, c0 = blockIdx.y * 64;
  const int t = threadIdx.x;
  {
    const int r = t >> 2, q4 = (t & 3) * 16;
    size_t ib = ((size_t)(b * N_ + n0 + r)) * C_ + c0 + q4;
#pragma unroll
    for (int j = 0; j < 4; ++j) {
      float4 mv = *(const float4*)(meanb + ib + j * 4);
      float4 sv = *(const float4*)(secb + ib + j * 4);
      ldM[r][q4 + j * 4 + 0] = mv.x; ldM[r][q4 + j * 4 + 1] = mv.y;
      ldM[r][q4 + j * 4 + 2] = mv.z; ldM[r][q4 + j * 4 + 3] = mv.w;
      ldS[r][q4 + j * 4 + 0] = sv.x; ldS[r][q4 + j * 4 + 1] = sv.y;
      ldS[r][q4 + j * 4 + 2] = sv.z; ldS[r][q4 + j * 4 + 3] = sv.w;
    }
  }
  __syncthreads();
  const int n4 = (t & 15) * 4, cb = t >> 4;
#pragma unroll
  for (int cc = 0; cc < 4; ++cc) {
    int c_loc = cc * 16 + cb;
    int c = c0 + c_loc;
    float mu = stats[(size_t)(b * C_ + c) * 2 + 0];
    float rs = stats[(size_t)(b * C_ + c) * 2 + 1];
    size_t gb = ((size_t)(b * C_ + c)) * N_ + n0 + n4;
    float4 xv = *(const float4*)(content + gb);
    float4 ov;
    {
      float m0_ = ldM[n4 + 0][c_loc], s0_ = ldS[n4 + 0][c_loc];
      float m1_ = ldM[n4 + 1][c_loc], s1_ = ldS[n4 + 1][c_loc];
      float m2_ = ldM[n4 + 2][c_loc], s2_ = ldS[n4 + 2][c_loc];
      float m3_ = ldM[n4 + 3][c_loc], s3_ = ldS[n4 + 3][c_loc];
      ov.x = sqrtf(fmaxf(s0_ - m0_ * m0_, 0.f)) * ((xv.x - mu) * rs) + m0_;
      ov.y = sqrtf(fmaxf(s1_ - m1_ * m1_, 0.f)) * ((xv.y - mu) * rs) + m1_;
      ov.z = sqrtf(fmaxf(s2_ - m2_ * m2_, 0.f)) * ((xv.z - mu) * rs) + m2_;
      ov.w = sqrtf(fmaxf(s3_ - m3_ * m3_, 0.f)) * ((xv.w - mu) * rs) + m3_;
    }
    *(float4*)(outp + gb) = ov;
  }
}

extern "C" void kernel_launch(void* const* d_in, const int* in_sizes, int n_in,
                              void* d_out, int out_size, void* d_ws, size_t ws_size,
                              hipStream_t stream) {
  (void)in_sizes; (void)n_in; (void)out_size; (void)ws_size;
  const float* content = (const float*)d_in[0];
  const float* style   = (const float*)d_in[1];
  const float* ckey    = (const float*)d_in[2];
  const float* skey    = (const float*)d_in[3];
  const float* Wf = (const float*)d_in[4]; const float* bf_ = (const float*)d_in[5];
  const float* Wg = (const float*)d_in[6]; const float* bg_ = (const float*)d_in[7];
  const float* Wh = (const float*)d_in[8]; const float* bh_ = (const float*)d_in[9];
  float* outp = (float*)d_out;
  char* ws = (char*)d_ws;

  const size_t MB = 1u << 20;
  u16*   Ft    = (u16*)(ws + 0 * MB);    // [B][N][C] f16
  u16*   Gt    = (u16*)(ws + 16 * MB);   // [B][M][C] f16
  u16*   Hv    = (u16*)(ws + 32 * MB);   // [B][C][M] f16
  float* stats = (float*)(ws + 48 * MB); // [B][C][2] fp32 (after Xt dead)
  u16*   Xt    = (u16*)(ws + 48 * MB);   // scratch, dead after convH
  float* meanb = (float*)(ws + 64 * MB); // [B][N][C] fp32
  float* secb  = (float*)(ws + 96 * MB); // [B][N][C] fp32
  u16*   Hvt   = (u16*)(ws + 64 * MB);   // scratch, dead before attn
  u16*   Wb3   = (u16*)(ws + 80 * MB);   // weights, dead before attn
  u16* Wbf = Wb3, *Wbg = Wb3 + 262144, *Wbh = Wb3 + 524288;

  const dim3 gT(64, 8, 4);

  cast_w_kernel<<<256, 256, 0, stream>>>(Wf, Wbf, 262144);
  cast_w_kernel<<<256, 256, 0, stream>>>(Wg, Wbg, 262144);
  cast_w_kernel<<<256, 256, 0, stream>>>(Wh, Wbh, 262144);

  transpose_cast_kernel<<<gT, 256, 0, stream>>>(ckey, Xt);
  conv_kernel<<<gT, 512, 0, stream>>>(Xt, Wbf, bf_, Ft);
  transpose_cast_kernel<<<gT, 256, 0, stream>>>(skey, Xt);
  conv_kernel<<<gT, 512, 0, stream>>>(Xt, Wbg, bg_, Gt);
  transpose_cast_kernel<<<gT, 256, 0, stream>>>(style, Xt);
  conv_kernel<<<gT, 512, 0, stream>>>(Xt, Wbh, bh_, Hvt);
  transpose_h_kernel<<<gT, 256, 0, stream>>>(Hvt, Hv);

  stats_kernel<<<dim3(C_, B_), 256, 0, stream>>>(content, stats);
  attn_dual_kernel<<<dim3(64, B_), 1024, 0, stream>>>(Ft, Gt, Hv, meanb, secb);
  combine_kernel<<<gT, 256, 0, stream>>>(content, meanb, secb, stats, outp);
}

// Round 17
// 1016.080 us; speedup vs baseline: 1.8174x; 1.1158x over previous
//
#include <hip/hip_runtime.h>

#define B_ 4
#define C_ 512
#define N_ 4096   // H*W == M (style spatial) == N (content spatial)

typedef unsigned short u16;
typedef _Float16 f16;
typedef f16 f16x8 __attribute__((ext_vector_type(8)));
typedef float f32x4 __attribute__((ext_vector_type(4)));

#define MFMA16(a, b, c) __builtin_amdgcn_mfma_f32_16x16x32_f16(a, b, c, 0, 0, 0)

__device__ __forceinline__ u16 f2h(float f) {
  union { f16 h; u16 u; } x; x.h = (f16)f; return x.u;   // v_cvt_f16_f32, RNE
}
__device__ __forceinline__ float h2f(u16 v) {
  union { u16 u; f16 h; } x; x.u = v; return (float)x.h;
}
__device__ __forceinline__ f16x8 ldA(const void* p) {
  union { uint4 u; f16x8 v; } x; x.u = *(const uint4*)p; return x.v;
}

// ---------------- weights fp32 -> f16 ----------------
__global__ __launch_bounds__(256) void cast_w_kernel(const float* __restrict__ in,
                                                     u16* __restrict__ out, int n) {
  int i = (blockIdx.x * 256 + threadIdx.x) * 4;
  if (i >= n) return;
  float4 v = *(const float4*)(in + i);
  uint2 p;
  p.x = f2h(v.x) | ((unsigned)f2h(v.y) << 16);
  p.y = f2h(v.z) | ((unsigned)f2h(v.w) << 16);
  *(uint2*)(out + i) = p;
}

// ---------------- fp32 [B][C][N] -> f16 [B][N][C] ----------------
__global__ __launch_bounds__(256) void transpose_cast_kernel(const float* __restrict__ in,
                                                             u16* __restrict__ out) {
  __shared__ float ld[64][65];
  const int b = blockIdx.z, n0 = blockIdx.x * 64, c0 = blockIdx.y * 64;
  const int t = threadIdx.x;
  {
    const int r = t >> 2, q4 = (t & 3) * 16;
    const float* ip = in + ((size_t)(b * C_ + c0 + r)) * N_ + n0 + q4;
#pragma unroll
    for (int j = 0; j < 4; ++j) {
      float4 v = *(const float4*)(ip + j * 4);
      ld[r][q4 + j * 4 + 0] = v.x; ld[r][q4 + j * 4 + 1] = v.y;
      ld[r][q4 + j * 4 + 2] = v.z; ld[r][q4 + j * 4 + 3] = v.w;
    }
  }
  __syncthreads();
  {
    const int r2 = t >> 2, c16 = (t & 3) * 16;
    unsigned pk[8];
#pragma unroll
    for (int j = 0; j < 8; ++j) {
      unsigned lo = f2h(ld[c16 + j * 2 + 0][r2]);
      unsigned hi = f2h(ld[c16 + j * 2 + 1][r2]);
      pk[j] = lo | (hi << 16);
    }
    u16* op = out + ((size_t)(b * N_ + n0 + r2)) * C_ + c0 + c16;
    *(uint4*)(op + 0) = make_uint4(pk[0], pk[1], pk[2], pk[3]);
    *(uint4*)(op + 8) = make_uint4(pk[4], pk[5], pk[6], pk[7]);
  }
}

// ---- conv1x1: out[b][n][o] = sum_c Xt[b][n][c]*W[o][c] + bias[o]
//      OutT != null: ALSO skip [n][c] write and emit transposed [o][n] (for Hv) ----
__global__ __launch_bounds__(512, 4) void conv_kernel(const u16* __restrict__ Xt,
                                                      const u16* __restrict__ Wb,
                                                      const float* __restrict__ bias,
                                                      u16* __restrict__ Outp,
                                                      u16* __restrict__ OutT) {
  __shared__ char sm[65536];
  const int b = blockIdx.z, n0 = blockIdx.x * 64, o0 = blockIdx.y * 64;
  const int t = threadIdx.x, w = t >> 6, lane = t & 63;
  const int wr = w >> 1, wc = w & 1, l15 = lane & 15, l4 = lane >> 4;
#pragma unroll
  for (int k = 0; k < 8; ++k) {
    int ch = t + k * 512, row = ch >> 6, c16 = ch & 63;
    uint4 xv = *(const uint4*)(Xt + ((size_t)(b * N_ + n0 + row)) * C_ + c16 * 8);
    *(uint4*)(sm + row * 1024 + ((c16 ^ (row & 7)) << 4)) = xv;
  }
  __syncthreads();
  f32x4 acc0 = {0, 0, 0, 0}, acc1 = {0, 0, 0, 0};
  const int arow = wr * 16 + l15;
  const int oA = o0 + wc * 32 + l15, oB = oA + 16;
  const u16* wp0 = Wb + (size_t)oA * C_ + l4 * 8;
  const u16* wp1 = Wb + (size_t)oB * C_ + l4 * 8;
#pragma unroll
  for (int kf = 0; kf < 16; ++kf) {
    f16x8 a = ldA(sm + arow * 1024 + (((kf * 4 + l4) ^ (arow & 7)) << 4));
    f16x8 w0 = ldA(wp0 + kf * 32);
    f16x8 w1 = ldA(wp1 + kf * 32);
    acc0 = MFMA16(a, w0, acc0);
    acc1 = MFMA16(a, w1, acc1);
  }
  const float b0 = bias[oA], b1 = bias[oB];
  if (OutT == nullptr) {
#pragma unroll
    for (int r = 0; r < 4; ++r) {
      int n = n0 + wr * 16 + l4 * 4 + r;
      size_t base = ((size_t)(b * N_ + n)) * C_;
      Outp[base + oA] = f2h(acc0[r] + b0);
      Outp[base + oB] = f2h(acc1[r] + b1);
    }
  } else {
    // transposed epilogue: bounce via LDS [64 o][72 u16], coalesced 16B writes
    __syncthreads();                                    // all MFMA LDS reads done
    u16* ldsT = (u16*)sm;
#pragma unroll
    for (int r = 0; r < 4; ++r) {
      int nl = wr * 16 + l4 * 4 + r;
      ldsT[(oA - o0) * 72 + nl] = f2h(acc0[r] + b0);
      ldsT[(oB - o0) * 72 + nl] = f2h(acc1[r] + b1);
    }
    __syncthreads();
    const int orow = t >> 3, n8 = (t & 7) * 8;
    uint4 v = *(const uint4*)&ldsT[orow * 72 + n8];
    *(uint4*)(OutT + ((size_t)(b * C_ + o0 + orow)) * N_ + n0 + n8) = v;
  }
}

// ====== fused dual-moment flash attention — R14 + de-conflicted S tile (144B rows) ======
// OutM[b][n][c] (f32) = softmax(F G) @ V^T ; OutS = softmax(F G) @ (V^2)^T
// R14 structure (Q in LDS, G/V time-share one buffer, 4 barriers, tight staging).
// Single change: S tile rows padded to 144B, NO xor swizzle — bank stride 4 spreads
// both the b16 P-writes and b128 A-frag reads (was ~8-way conflicted).
#define LQ  0        // Q tile [64 n][512 c] f16, xor-swizzled rows of 1024B
#define LGV 65536    // G [64 m][512 c] (QK) / V [512 c][64 m] (PV), time-shared
#define LS  131072   // S tile [64 n] rows of 144B, f16, UNswizzled
#define LPM 140288   // pmax float [4][64]
#define LPS 141312   // psum float [4][64]

__global__ __launch_bounds__(1024, 4) void attn_dual_kernel(const u16* __restrict__ Ft,
                                                            const u16* __restrict__ Gt,
                                                            const u16* __restrict__ V,
                                                            float* __restrict__ OutM,
                                                            float* __restrict__ OutS) {
  __shared__ char sm[142336];
  char* ldsQ = sm + LQ; char* ldsGV = sm + LGV; char* ldsS = sm + LS;
  float* pmax = (float*)(sm + LPM);
  float* psum = (float*)(sm + LPS);

  const int b = blockIdx.y, n0 = blockIdx.x * 64;
  const int t = threadIdx.x, w = t >> 6, lane = t & 63;
  const int ri = w >> 2, mi = w & 3;                    // QK: row-group x m-quarter; PV: row-group x c-eighth
  const int l15 = lane & 15, l4 = lane >> 4;

  // ---- prologue: stage Q once ----
#pragma unroll
  for (int k = 0; k < 4; ++k) {
    int ch = t + k * 1024, row = ch >> 6, c16 = ch & 63;
    uint4 qv = *(const uint4*)(Ft + ((size_t)(b * N_ + n0 + row)) * C_ + c16 * 8);
    *(uint4*)(ldsQ + row * 1024 + ((c16 ^ (row & 7)) << 4)) = qv;
  }

  f32x4 accM[8], accS[8];
#pragma unroll
  for (int i = 0; i < 8; ++i) { accM[i] = (f32x4){0,0,0,0}; accS[i] = (f32x4){0,0,0,0}; }
  float m_run[4] = {-1e30f, -1e30f, -1e30f, -1e30f};
  float l_run[4] = {0, 0, 0, 0};

  const u16* Vb = V + (size_t)(b * C_) * N_;
  __syncthreads();                                      // Q resident

  for (int it = 0; it < 64; ++it) {
    const int m0 = it * 64;
    // ---- stage G(it) [64 m][512 c] (tight load->write) ----
#pragma unroll
    for (int k = 0; k < 4; ++k) {
      int ch = t + k * 1024, row = ch >> 6, c16 = ch & 63;
      uint4 gv = *(const uint4*)(Gt + ((size_t)(b * N_ + m0 + row)) * C_ + c16 * 8);
      *(uint4*)(ldsGV + row * 1024 + ((c16 ^ (row & 7)) << 4)) = gv;
    }
    __syncthreads();                                    // B1: G resident

    // ---- QK^T: wave -> S[16 n (ri) x 16 m (mi)] ----
    f32x4 s0 = {0, 0, 0, 0};
    {
      const int qrow = ri * 16 + l15;
      const int grow = mi * 16 + l15;
#pragma unroll
      for (int kf = 0; kf < 16; ++kf) {
        f16x8 qf = ldA(ldsQ + qrow * 1024 + (((kf * 4 + l4) ^ (qrow & 7)) << 4));
        f16x8 gf = ldA(ldsGV + grow * 1024 + (((kf * 4 + l4) ^ (grow & 7)) << 4));
        s0 = MFMA16(qf, gf, s0);
      }
    }
    // quarter row-max (16-lane butterfly) -> pmax
    float rmax[4];
#pragma unroll
    for (int r = 0; r < 4; ++r) rmax[r] = s0[r];
#pragma unroll
    for (int off = 1; off < 16; off <<= 1)
#pragma unroll
      for (int r = 0; r < 4; ++r) rmax[r] = fmaxf(rmax[r], __shfl_xor(rmax[r], off));
    if (l15 == 0)
#pragma unroll
      for (int r = 0; r < 4; ++r) pmax[mi * 64 + ri * 16 + l4 * 4 + r] = rmax[r];
    __syncthreads();                                    // B2: pmax ready; ALL G reads done

    // ---- softmax (exchanged) ----
    float fac[4], mnew[4], rsum[4];
#pragma unroll
    for (int r = 0; r < 4; ++r) {
      int row = ri * 16 + l4 * 4 + r;
      float mt = fmaxf(fmaxf(pmax[row], pmax[64 + row]),
                       fmaxf(pmax[128 + row], pmax[192 + row]));
      float mn = fmaxf(m_run[r], mt);
      fac[r] = __expf(m_run[r] - mn);
      m_run[r] = mn; mnew[r] = mn;
    }
#pragma unroll
    for (int r = 0; r < 4; ++r) {
      float p0 = __expf(s0[r] - mnew[r]);
      u16 pb0 = f2h(p0);
      rsum[r] = h2f(pb0);                               // denominator from ROUNDED p
      int row = ri * 16 + l4 * 4 + r;
      int m = mi * 16 + l15;
      *(u16*)(ldsS + row * 144 + m * 2) = pb0;          // plain layout, 144B rows
    }
#pragma unroll
    for (int off = 1; off < 16; off <<= 1)
#pragma unroll
      for (int r = 0; r < 4; ++r) rsum[r] += __shfl_xor(rsum[r], off);
    if (l15 == 0)
#pragma unroll
      for (int r = 0; r < 4; ++r) psum[mi * 64 + ri * 16 + l4 * 4 + r] = rsum[r];

    // ---- stage V(it) [512 c][64 m] into the SAME buffer (G dead since B2); tight ----
#pragma unroll
    for (int k = 0; k < 4; ++k) {
      int ch = t + k * 1024, c = ch >> 3, sl = ch & 7;
      uint4 vv = *(const uint4*)(Vb + (size_t)c * N_ + m0 + sl * 8);
      *(uint4*)(ldsGV + c * 128 + ((sl ^ (c & 7)) << 4)) = vv;
    }
    __syncthreads();                                    // B3: V + S + psum ready

    // ---- l update, rescale, dual PV (S and V from LDS) ----
#pragma unroll
    for (int r = 0; r < 4; ++r) {
      int row = ri * 16 + l4 * 4 + r;
      l_run[r] = l_run[r] * fac[r] +
                 ((psum[row] + psum[64 + row]) + (psum[128 + row] + psum[192 + row]));
    }
    bool nch = true;
#pragma unroll
    for (int r = 0; r < 4; ++r) nch = nch && (fac[r] == 1.0f);
    if (!__all(nch)) {
#pragma unroll
      for (int f = 0; f < 8; ++f)
#pragma unroll
        for (int r = 0; r < 4; ++r) { accM[f][r] *= fac[r]; accS[f][r] *= fac[r]; }
    }
    const int srow = ri * 16 + l15;
    f16x8 a0 = ldA(ldsS + srow * 144 + (0 + l4) * 16);
    f16x8 a1 = ldA(ldsS + srow * 144 + (4 + l4) * 16);
#pragma unroll
    for (int f = 0; f < 8; ++f) {
      const int c = mi * 128 + f * 16 + l15;
      f16x8 v0 = ldA(ldsGV + c * 128 + (((0 + l4) ^ (c & 7)) << 4));
      f16x8 v1 = ldA(ldsGV + c * 128 + (((4 + l4) ^ (c & 7)) << 4));
      accM[f] = MFMA16(a0, v0, accM[f]);
      accM[f] = MFMA16(a1, v1, accM[f]);
      f16x8 w0 = v0 * v0, w1 = v1 * v1;                 // f16 RNE squares
      accS[f] = MFMA16(a0, w0, accS[f]);
      accS[f] = MFMA16(a1, w1, accS[f]);
    }
    __syncthreads();                                    // B4: PV V-reads done; buffer free
  }

  // ---- epilogue: f32 outputs ----
  float rl[4];
#pragma unroll
  for (int r = 0; r < 4; ++r) rl[r] = 1.0f / l_run[r];
#pragma unroll
  for (int f = 0; f < 8; ++f) {
    const int c = mi * 128 + f * 16 + l15;
#pragma unroll
    for (int r = 0; r < 4; ++r) {
      int n = n0 + ri * 16 + l4 * 4 + r;
      size_t o = ((size_t)(b * N_ + n)) * C_ + c;
      OutM[o] = accM[f][r] * rl[r];
      OutS[o] = accS[f][r] * rl[r];
    }
  }
}

// ---------------- per-(b,c) content stats ----------------
__global__ __launch_bounds__(256) void stats_kernel(const float* __restrict__ content,
                                                    float* __restrict__ stats) {
  const int c = blockIdx.x, b = blockIdx.y;
  const float4* p = (const float4*)(content + ((size_t)(b * C_ + c)) * N_);
  float s = 0.f, ss = 0.f;
  for (int i = threadIdx.x; i < N_ / 4; i += 256) {
    float4 v = p[i];
    s += v.x + v.y + v.z + v.w;
    ss += v.x * v.x + v.y * v.y + v.z * v.z + v.w * v.w;
  }
#pragma unroll
  for (int off = 32; off; off >>= 1) { s += __shfl_down(s, off); ss += __shfl_down(ss, off); }
  __shared__ float as_[4], ass_[4];
  int w = threadIdx.x >> 6;
  if ((threadIdx.x & 63) == 0) { as_[w] = s; ass_[w] = ss; }
  __syncthreads();
  if (threadIdx.x == 0) {
    float S = as_[0] + as_[1] + as_[2] + as_[3];
    float SS = ass_[0] + ass_[1] + ass_[2] + ass_[3];
    float mu = S * (1.0f / N_);
    float var = (SS - (float)N_ * mu * mu) * (1.0f / (N_ - 1));
    stats[(size_t)(b * C_ + c) * 2 + 0] = mu;
    stats[(size_t)(b * C_ + c) * 2 + 1] = rsqrtf(var + 1e-5f);
  }
}

// ---------------- out[b][c][n] = sqrt(relu(sec-mean^2))*(x-mu)*rs + mean ----------------
__global__ __launch_bounds__(256) void combine_kernel(const float* __restrict__ content,
                                                      const float* __restrict__ meanb,
                                                      const float* __restrict__ secb,
                                                      const float* __restrict__ stats,
                                                      float* __restrict__ outp) {
  __shared__ float ldM[64][65], ldS[64][65];
  const int b = blockIdx.z, n0 = blockIdx.x * 64, c0 = blockIdx.y * 64;
  const int t = threadIdx.x;
  {
    const int r = t >> 2, q4 = (t & 3) * 16;
    size_t ib = ((size_t)(b * N_ + n0 + r)) * C_ + c0 + q4;
#pragma unroll
    for (int j = 0; j < 4; ++j) {
      float4 mv = *(const float4*)(meanb + ib + j * 4);
      float4 sv = *(const float4*)(secb + ib + j * 4);
      ldM[r][q4 + j * 4 + 0] = mv.x; ldM[r][q4 + j * 4 + 1] = mv.y;
      ldM[r][q4 + j * 4 + 2] = mv.z; ldM[r][q4 + j * 4 + 3] = mv.w;
      ldS[r][q4 + j * 4 + 0] = sv.x; ldS[r][q4 + j * 4 + 1] = sv.y;
      ldS[r][q4 + j * 4 + 2] = sv.z; ldS[r][q4 + j * 4 + 3] = sv.w;
    }
  }
  __syncthreads();
  const int n4 = (t & 15) * 4, cb = t >> 4;
#pragma unroll
  for (int cc = 0; cc < 4; ++cc) {
    int c_loc = cc * 16 + cb;
    int c = c0 + c_loc;
    float mu = stats[(size_t)(b * C_ + c) * 2 + 0];
    float rs = stats[(size_t)(b * C_ + c) * 2 + 1];
    size_t gb = ((size_t)(b * C_ + c)) * N_ + n0 + n4;
    float4 xv = *(const float4*)(content + gb);
    float4 ov;
    {
      float m0_ = ldM[n4 + 0][c_loc], s0_ = ldS[n4 + 0][c_loc];
      float m1_ = ldM[n4 + 1][c_loc], s1_ = ldS[n4 + 1][c_loc];
      float m2_ = ldM[n4 + 2][c_loc], s2_ = ldS[n4 + 2][c_loc];
      float m3_ = ldM[n4 + 3][c_loc], s3_ = ldS[n4 + 3][c_loc];
      ov.x = sqrtf(fmaxf(s0_ - m0_ * m0_, 0.f)) * ((xv.x - mu) * rs) + m0_;
      ov.y = sqrtf(fmaxf(s1_ - m1_ * m1_, 0.f)) * ((xv.y - mu) * rs) + m1_;
      ov.z = sqrtf(fmaxf(s2_ - m2_ * m2_, 0.f)) * ((xv.z - mu) * rs) + m2_;
      ov.w = sqrtf(fmaxf(s3_ - m3_ * m3_, 0.f)) * ((xv.w - mu) * rs) + m3_;
    }
    *(float4*)(outp + gb) = ov;
  }
}

extern "C" void kernel_launch(void* const* d_in, const int* in_sizes, int n_in,
                              void* d_out, int out_size, void* d_ws, size_t ws_size,
                              hipStream_t stream) {
  (void)in_sizes; (void)n_in; (void)out_size; (void)ws_size;
  const float* content = (const float*)d_in[0];
  const float* style   = (const float*)d_in[1];
  const float* ckey    = (const float*)d_in[2];
  const float* skey    = (const float*)d_in[3];
  const float* Wf = (const float*)d_in[4]; const float* bf_ = (const float*)d_in[5];
  const float* Wg = (const float*)d_in[6]; const float* bg_ = (const float*)d_in[7];
  const float* Wh = (const float*)d_in[8]; const float* bh_ = (const float*)d_in[9];
  float* outp = (float*)d_out;
  char* ws = (char*)d_ws;

  const size_t MB = 1u << 20;
  u16*   Ft    = (u16*)(ws + 0 * MB);    // [B][N][C] f16
  u16*   Gt    = (u16*)(ws + 16 * MB);   // [B][M][C] f16
  u16*   Hv    = (u16*)(ws + 32 * MB);   // [B][C][M] f16 (written by conv-H directly)
  float* stats = (float*)(ws + 48 * MB); // [B][C][2] fp32 (after Xt dead)
  u16*   Xt    = (u16*)(ws + 48 * MB);   // scratch, dead after convH
  float* meanb = (float*)(ws + 64 * MB); // [B][N][C] fp32
  float* secb  = (float*)(ws + 96 * MB); // [B][N][C] fp32
  u16*   Wb3   = (u16*)(ws + 80 * MB);   // weights, dead before attn
  u16* Wbf = Wb3, *Wbg = Wb3 + 262144, *Wbh = Wb3 + 524288;

  const dim3 gT(64, 8, 4);

  cast_w_kernel<<<256, 256, 0, stream>>>(Wf, Wbf, 262144);
  cast_w_kernel<<<256, 256, 0, stream>>>(Wg, Wbg, 262144);
  cast_w_kernel<<<256, 256, 0, stream>>>(Wh, Wbh, 262144);

  transpose_cast_kernel<<<gT, 256, 0, stream>>>(ckey, Xt);
  conv_kernel<<<gT, 512, 0, stream>>>(Xt, Wbf, bf_, Ft, nullptr);
  transpose_cast_kernel<<<gT, 256, 0, stream>>>(skey, Xt);
  conv_kernel<<<gT, 512, 0, stream>>>(Xt, Wbg, bg_, Gt, nullptr);
  transpose_cast_kernel<<<gT, 256, 0, stream>>>(style, Xt);
  conv_kernel<<<gT, 512, 0, stream>>>(Xt, Wbh, bh_, nullptr, Hv);   // transposed epilogue

  stats_kernel<<<dim3(C_, B_), 256, 0, stream>>>(content, stats);
  attn_dual_kernel<<<dim3(64, B_), 1024, 0, stream>>>(Ft, Gt, Hv, meanb, secb);
  combine_kernel<<<gT, 256, 0, stream>>>(content, meanb, secb, stats, outp);
}